// Round 1
// baseline (240.767 us; speedup 1.0000x reference)
//
#include <hip/hip_runtime.h>
#include <math.h>

#define MPTS 2048
#define NBATCH 8
#define NT 32            // MPTS / 64 candidates per lane

// Count, across the whole wave, how many of the 2048 d2 values are <= t.
// All 64 lanes active (uniform control flow). Result is wave-uniform.
static __device__ __forceinline__ int count_le(const float* d, float t) {
  int c = 0;
#pragma unroll
  for (int k = 0; k < NT; ++k)
    c += __popcll(__ballot(d[k] <= t));
  return c;
}

// Threshold tau such that {d <= tau} == the 64 smallest values (clamped at rmax2).
// If <=64 values lie within rmax2, no truncation: return rmax2.
static __device__ __forceinline__ float kth_thr(const float* d, float rmax2) {
  int c = count_le(d, rmax2);
  if (c <= 64) return rmax2;          // wave-uniform branch
  float lo = 0.f, hi = rmax2;         // invariant: count(lo) < 64 <= count(hi)
  for (int it = 0; it < 24; ++it) {
    float mid = 0.5f * (lo + hi);
    if (count_le(d, mid) >= 64) hi = mid; else lo = mid;
  }
  return hi;
}

// Kernel A: per point i -> tau3 (3D 64th-smallest d2) and x_centers for the
// 3 scales (masked mean of x over 6D top-64 within r6).
// xc layout (planar): xc[((s*NBATCH + b)*3 + dim)*MPTS + i]
__global__ __launch_bounds__(256) void kernelA(
    const float* __restrict__ x, const float* __restrict__ pos,
    float* __restrict__ xc, float* __restrict__ tau3) {
  const int wid  = (blockIdx.x * 256 + threadIdx.x) >> 6;
  const int lane = threadIdx.x & 63;
  const int b = wid >> 11;
  const int i = wid & (MPTS - 1);
  const float* posb = pos + b * MPTS * 3;
  const float* xb   = x   + b * MPTS * 3;

  const float pix = posb[3*i+0], piy = posb[3*i+1], piz = posb[3*i+2];
  const float xix = xb[3*i+0],   xiy = xb[3*i+1],   xiz = xb[3*i+2];

  float d3a[NT], d6a[NT];
#pragma unroll
  for (int k = 0; k < NT; ++k) {
    const int j = k * 64 + lane;
    const float dx = posb[3*j+0] - pix;
    const float dy = posb[3*j+1] - piy;
    const float dz = posb[3*j+2] - piz;
    const float a3 = dx*dx + dy*dy + dz*dz;
    const float ex = xb[3*j+0] - xix;
    const float ey = xb[3*j+1] - xiy;
    const float ez = xb[3*j+2] - xiz;
    d3a[k] = a3;
    d6a[k] = a3 + ex*ex + ey*ey + ez*ez;
  }

  const float t6 = kth_thr(d6a, 0.45f * 0.45f);
  const float t3 = kth_thr(d3a, 0.40f * 0.40f);

  // nested thresholds: thr0 <= thr1 <= thr2 (= t6, since t6 <= 0.45^2)
  const float thr0 = fminf(0.15f * 0.15f, t6);
  const float thr1 = fminf(0.25f * 0.25f, t6);
  const float thr2 = t6;

  float vals[12];  // {sx,sy,sz,n} x 3 scales
#pragma unroll
  for (int v = 0; v < 12; ++v) vals[v] = 0.f;

#pragma unroll
  for (int k = 0; k < NT; ++k) {
    if (d6a[k] <= thr2) {
      const int j = k * 64 + lane;
      const float xjx = xb[3*j+0], xjy = xb[3*j+1], xjz = xb[3*j+2];
      vals[8] += xjx; vals[9] += xjy; vals[10] += xjz; vals[11] += 1.f;
      if (d6a[k] <= thr1) {
        vals[4] += xjx; vals[5] += xjy; vals[6] += xjz; vals[7] += 1.f;
        if (d6a[k] <= thr0) {
          vals[0] += xjx; vals[1] += xjy; vals[2] += xjz; vals[3] += 1.f;
        }
      }
    }
  }

#pragma unroll
  for (int v = 0; v < 12; ++v)
#pragma unroll
    for (int off = 32; off > 0; off >>= 1)
      vals[v] += __shfl_xor(vals[v], off, 64);

  if (lane == 0) {
#pragma unroll
    for (int s = 0; s < 3; ++s) {
      const float inv = 1.f / vals[4*s + 3];   // count >= 1 (self edge)
      float* base = xc + (size_t)((s * NBATCH + b) * 3) * MPTS;
      base[0*MPTS + i] = vals[4*s + 0] * inv;
      base[1*MPTS + i] = vals[4*s + 1] * inv;
      base[2*MPTS + i] = vals[4*s + 2] * inv;
    }
    tau3[b * MPTS + i] = t3;
  }
}

// Kernel B: per point i -> msg_s = mean over 3D-selected j of ||xc_i - xc_j||,
// then sigmoid(w.msg + b).
__global__ __launch_bounds__(256) void kernelB(
    const float* __restrict__ pos, const float* __restrict__ wlin,
    const float* __restrict__ blin, const float* __restrict__ xc,
    const float* __restrict__ tau3, float* __restrict__ out) {
  const int wid  = (blockIdx.x * 256 + threadIdx.x) >> 6;
  const int lane = threadIdx.x & 63;
  const int b = wid >> 11;
  const int i = wid & (MPTS - 1);
  const float* posb = pos + b * MPTS * 3;

  const float pix = posb[3*i+0], piy = posb[3*i+1], piz = posb[3*i+2];
  const float t3 = tau3[b * MPTS + i];

  const float thr0 = fminf(0.1f * 0.1f, t3);
  const float thr1 = fminf(0.2f * 0.2f, t3);
  const float thr2 = t3;  // t3 <= 0.4^2 always

  const float* xc0 = xc + (size_t)((0 * NBATCH + b) * 3) * MPTS;
  const float* xc1 = xc + (size_t)((1 * NBATCH + b) * 3) * MPTS;
  const float* xc2 = xc + (size_t)((2 * NBATCH + b) * 3) * MPTS;

  const float c0x = xc0[0*MPTS+i], c0y = xc0[1*MPTS+i], c0z = xc0[2*MPTS+i];
  const float c1x = xc1[0*MPTS+i], c1y = xc1[1*MPTS+i], c1z = xc1[2*MPTS+i];
  const float c2x = xc2[0*MPTS+i], c2y = xc2[1*MPTS+i], c2z = xc2[2*MPTS+i];

  float s0 = 0.f, s1 = 0.f, s2 = 0.f, n0 = 0.f, n1 = 0.f, n2 = 0.f;

  for (int k = 0; k < NT; ++k) {
    const int j = k * 64 + lane;
    const float dx = posb[3*j+0] - pix;
    const float dy = posb[3*j+1] - piy;
    const float dz = posb[3*j+2] - piz;
    const float a3 = dx*dx + dy*dy + dz*dz;
    if (a3 <= thr2) {
      {
        const float ux = c2x - xc2[0*MPTS+j];
        const float uy = c2y - xc2[1*MPTS+j];
        const float uz = c2z - xc2[2*MPTS+j];
        s2 += sqrtf(fmaxf(ux*ux + uy*uy + uz*uz, 1e-12f)); n2 += 1.f;
      }
      if (a3 <= thr1) {
        const float ux = c1x - xc1[0*MPTS+j];
        const float uy = c1y - xc1[1*MPTS+j];
        const float uz = c1z - xc1[2*MPTS+j];
        s1 += sqrtf(fmaxf(ux*ux + uy*uy + uz*uz, 1e-12f)); n1 += 1.f;
        if (a3 <= thr0) {
          const float ux = c0x - xc0[0*MPTS+j];
          const float uy = c0y - xc0[1*MPTS+j];
          const float uz = c0z - xc0[2*MPTS+j];
          s0 += sqrtf(fmaxf(ux*ux + uy*uy + uz*uz, 1e-12f)); n0 += 1.f;
        }
      }
    }
  }

  float vals[6] = {s0, s1, s2, n0, n1, n2};
#pragma unroll
  for (int v = 0; v < 6; ++v)
#pragma unroll
    for (int off = 32; off > 0; off >>= 1)
      vals[v] += __shfl_xor(vals[v], off, 64);

  if (lane == 0) {
    const float msg0 = vals[0] / vals[3];
    const float msg1 = vals[1] / vals[4];
    const float msg2 = vals[2] / vals[5];
    const float z = wlin[0]*msg0 + wlin[1]*msg1 + wlin[2]*msg2 + blin[0];
    out[b * MPTS + i] = 1.f / (1.f + expf(-z));
  }
}

extern "C" void kernel_launch(void* const* d_in, const int* in_sizes, int n_in,
                              void* d_out, int out_size, void* d_ws, size_t ws_size,
                              hipStream_t stream) {
  (void)in_sizes; (void)n_in; (void)out_size; (void)ws_size;
  const float* x    = (const float*)d_in[0];   // [8,2048,3]
  const float* pos  = (const float*)d_in[1];   // [8,2048,3]
  const float* wlin = (const float*)d_in[2];   // [1,3]
  const float* blin = (const float*)d_in[3];   // [1]
  float* xc   = (float*)d_ws;                  // 3*8*3*2048 floats (planar)
  float* tau3 = xc + 3 * NBATCH * 3 * MPTS;    // 16384 floats
  float* out  = (float*)d_out;

  const int nblocks = NBATCH * MPTS / 4;       // 4 waves (points) per 256-thread block
  kernelA<<<nblocks, 256, 0, stream>>>(x, pos, xc, tau3);
  kernelB<<<nblocks, 256, 0, stream>>>(pos, wlin, blin, xc, tau3, out);
}

// Round 2
// 193.905 us; speedup vs baseline: 1.2417x; 1.2417x over previous
//
#include <hip/hip_runtime.h>
#include <math.h>

#define MPTS 2048
#define NBATCH 8
#define NT 32            // MPTS / 64 candidates per lane

// Fused count pass: counts how many d3 <= t3 and d6 <= t6 across the wave.
// Two independent ballot chains interleaved for ILP. Wave-uniform results.
static __device__ __forceinline__ void count2(const float* d3, float t3,
                                              const float* d6, float t6,
                                              int& c3, int& c6) {
  int a = 0, b = 0;
#pragma unroll
  for (int k = 0; k < NT; ++k) {
    a += __popcll(__ballot(d3[k] <= t3));
    b += __popcll(__ballot(d6[k] <= t6));
  }
  c3 = a; c6 = b;
}

// Dual top-64 threshold search: finds t such that |{d <= t}| == 64 (or rmax2
// if fewer than 64 lie within). Regula-falsi + alternating bisection with
// early exit on exact count; both searches fused for ILP.
static __device__ __forceinline__ void kth_thr_dual(
    const float* d3, float r3max2, const float* d6, float r6max2,
    float& t3, float& t6) {
  int c3, c6;
  count2(d3, r3max2, d6, r6max2, c3, c6);
  float lo3 = 0.f, hi3 = r3max2; int clo3 = 0, chi3 = c3;
  float lo6 = 0.f, hi6 = r6max2; int clo6 = 0, chi6 = c6;
  bool done3 = (c3 <= 64), done6 = (c6 <= 64);
  for (int it = 0; it < 22 && !(done3 && done6); ++it) {
    float m3 = hi3, m6 = hi6;
    if (!done3) {
      float f;
      if (it & 1) {
        f = 0.5f;                                    // bisection safeguard
      } else {
        f = (64.5f - (float)clo3) / (float)(chi3 - clo3);
        f = fminf(fmaxf(f, 0.0625f), 0.9375f);       // guaranteed progress
      }
      m3 = lo3 + f * (hi3 - lo3);
    }
    if (!done6) {
      float f;
      if (it & 1) {
        f = 0.5f;
      } else {
        f = (64.5f - (float)clo6) / (float)(chi6 - clo6);
        f = fminf(fmaxf(f, 0.0625f), 0.9375f);
      }
      m6 = lo6 + f * (hi6 - lo6);
    }
    int n3, n6;
    count2(d3, m3, d6, m6, n3, n6);
    if (!done3) {
      if (n3 >= 64) { hi3 = m3; chi3 = n3; done3 = (n3 == 64); }
      else          { lo3 = m3; clo3 = n3; }
    }
    if (!done6) {
      if (n6 >= 64) { hi6 = m6; chi6 = n6; done6 = (n6 == 64); }
      else          { lo6 = m6; clo6 = n6; }
    }
  }
  t3 = hi3; t6 = hi6;
}

// Kernel A: per point i -> tau3 (3D 64th-smallest d2) and x_centers for the
// 3 scales (masked mean of x over 6D top-64 within r6).
// xc layout (planar): xc[((s*NBATCH + b)*3 + dim)*MPTS + i]
__global__ __launch_bounds__(256) void kernelA(
    const float* __restrict__ x, const float* __restrict__ pos,
    float* __restrict__ xc, float* __restrict__ tau3) {
  const int wid  = (blockIdx.x * 256 + threadIdx.x) >> 6;
  const int lane = threadIdx.x & 63;
  const int b = wid >> 11;
  const int i = wid & (MPTS - 1);
  const float* posb = pos + b * MPTS * 3;
  const float* xb   = x   + b * MPTS * 3;

  const float pix = posb[3*i+0], piy = posb[3*i+1], piz = posb[3*i+2];
  const float xix = xb[3*i+0],   xiy = xb[3*i+1],   xiz = xb[3*i+2];

  float d3a[NT], d6a[NT];
#pragma unroll
  for (int k = 0; k < NT; ++k) {
    const int j = k * 64 + lane;
    const float dx = posb[3*j+0] - pix;
    const float dy = posb[3*j+1] - piy;
    const float dz = posb[3*j+2] - piz;
    const float a3 = dx*dx + dy*dy + dz*dz;
    const float ex = xb[3*j+0] - xix;
    const float ey = xb[3*j+1] - xiy;
    const float ez = xb[3*j+2] - xiz;
    d3a[k] = a3;
    d6a[k] = a3 + ex*ex + ey*ey + ez*ez;
  }

  float t3, t6;
  kth_thr_dual(d3a, 0.40f * 0.40f, d6a, 0.45f * 0.45f, t3, t6);

  // nested thresholds: thr0 <= thr1 <= thr2 (= t6, since t6 <= 0.45^2)
  const float thr0 = fminf(0.15f * 0.15f, t6);
  const float thr1 = fminf(0.25f * 0.25f, t6);
  const float thr2 = t6;

  float vals[12];  // {sx,sy,sz,n} x 3 scales
#pragma unroll
  for (int v = 0; v < 12; ++v) vals[v] = 0.f;

#pragma unroll
  for (int k = 0; k < NT; ++k) {
    if (d6a[k] <= thr2) {
      const int j = k * 64 + lane;
      const float xjx = xb[3*j+0], xjy = xb[3*j+1], xjz = xb[3*j+2];
      vals[8] += xjx; vals[9] += xjy; vals[10] += xjz; vals[11] += 1.f;
      if (d6a[k] <= thr1) {
        vals[4] += xjx; vals[5] += xjy; vals[6] += xjz; vals[7] += 1.f;
        if (d6a[k] <= thr0) {
          vals[0] += xjx; vals[1] += xjy; vals[2] += xjz; vals[3] += 1.f;
        }
      }
    }
  }

#pragma unroll
  for (int v = 0; v < 12; ++v)
#pragma unroll
    for (int off = 32; off > 0; off >>= 1)
      vals[v] += __shfl_xor(vals[v], off, 64);

  if (lane == 0) {
#pragma unroll
    for (int s = 0; s < 3; ++s) {
      const float inv = 1.f / vals[4*s + 3];   // count >= 1 (self edge)
      float* base = xc + (size_t)((s * NBATCH + b) * 3) * MPTS;
      base[0*MPTS + i] = vals[4*s + 0] * inv;
      base[1*MPTS + i] = vals[4*s + 1] * inv;
      base[2*MPTS + i] = vals[4*s + 2] * inv;
    }
    tau3[b * MPTS + i] = t3;
  }
}

// Kernel B: per point i -> msg_s = mean over 3D-selected j of ||xc_i - xc_j||,
// then sigmoid(w.msg + b).
__global__ __launch_bounds__(256) void kernelB(
    const float* __restrict__ pos, const float* __restrict__ wlin,
    const float* __restrict__ blin, const float* __restrict__ xc,
    const float* __restrict__ tau3, float* __restrict__ out) {
  const int wid  = (blockIdx.x * 256 + threadIdx.x) >> 6;
  const int lane = threadIdx.x & 63;
  const int b = wid >> 11;
  const int i = wid & (MPTS - 1);
  const float* posb = pos + b * MPTS * 3;

  const float pix = posb[3*i+0], piy = posb[3*i+1], piz = posb[3*i+2];
  const float t3 = tau3[b * MPTS + i];

  const float thr0 = fminf(0.1f * 0.1f, t3);
  const float thr1 = fminf(0.2f * 0.2f, t3);
  const float thr2 = t3;  // t3 <= 0.4^2 always

  const float* xc0 = xc + (size_t)((0 * NBATCH + b) * 3) * MPTS;
  const float* xc1 = xc + (size_t)((1 * NBATCH + b) * 3) * MPTS;
  const float* xc2 = xc + (size_t)((2 * NBATCH + b) * 3) * MPTS;

  const float c0x = xc0[0*MPTS+i], c0y = xc0[1*MPTS+i], c0z = xc0[2*MPTS+i];
  const float c1x = xc1[0*MPTS+i], c1y = xc1[1*MPTS+i], c1z = xc1[2*MPTS+i];
  const float c2x = xc2[0*MPTS+i], c2y = xc2[1*MPTS+i], c2z = xc2[2*MPTS+i];

  float s0 = 0.f, s1 = 0.f, s2 = 0.f, n0 = 0.f, n1 = 0.f, n2 = 0.f;

  for (int k = 0; k < NT; ++k) {
    const int j = k * 64 + lane;
    const float dx = posb[3*j+0] - pix;
    const float dy = posb[3*j+1] - piy;
    const float dz = posb[3*j+2] - piz;
    const float a3 = dx*dx + dy*dy + dz*dz;
    if (a3 <= thr2) {
      {
        const float ux = c2x - xc2[0*MPTS+j];
        const float uy = c2y - xc2[1*MPTS+j];
        const float uz = c2z - xc2[2*MPTS+j];
        s2 += sqrtf(fmaxf(ux*ux + uy*uy + uz*uz, 1e-12f)); n2 += 1.f;
      }
      if (a3 <= thr1) {
        const float ux = c1x - xc1[0*MPTS+j];
        const float uy = c1y - xc1[1*MPTS+j];
        const float uz = c1z - xc1[2*MPTS+j];
        s1 += sqrtf(fmaxf(ux*ux + uy*uy + uz*uz, 1e-12f)); n1 += 1.f;
        if (a3 <= thr0) {
          const float ux = c0x - xc0[0*MPTS+j];
          const float uy = c0y - xc0[1*MPTS+j];
          const float uz = c0z - xc0[2*MPTS+j];
          s0 += sqrtf(fmaxf(ux*ux + uy*uy + uz*uz, 1e-12f)); n0 += 1.f;
        }
      }
    }
  }

  float vals[6] = {s0, s1, s2, n0, n1, n2};
#pragma unroll
  for (int v = 0; v < 6; ++v)
#pragma unroll
    for (int off = 32; off > 0; off >>= 1)
      vals[v] += __shfl_xor(vals[v], off, 64);

  if (lane == 0) {
    const float msg0 = vals[0] / vals[3];
    const float msg1 = vals[1] / vals[4];
    const float msg2 = vals[2] / vals[5];
    const float z = wlin[0]*msg0 + wlin[1]*msg1 + wlin[2]*msg2 + blin[0];
    out[b * MPTS + i] = 1.f / (1.f + expf(-z));
  }
}

extern "C" void kernel_launch(void* const* d_in, const int* in_sizes, int n_in,
                              void* d_out, int out_size, void* d_ws, size_t ws_size,
                              hipStream_t stream) {
  (void)in_sizes; (void)n_in; (void)out_size; (void)ws_size;
  const float* x    = (const float*)d_in[0];   // [8,2048,3]
  const float* pos  = (const float*)d_in[1];   // [8,2048,3]
  const float* wlin = (const float*)d_in[2];   // [1,3]
  const float* blin = (const float*)d_in[3];   // [1]
  float* xc   = (float*)d_ws;                  // 3*8*3*2048 floats (planar)
  float* tau3 = xc + 3 * NBATCH * 3 * MPTS;    // 16384 floats
  float* out  = (float*)d_out;

  const int nblocks = NBATCH * MPTS / 4;       // 4 waves (points) per 256-thread block
  kernelA<<<nblocks, 256, 0, stream>>>(x, pos, xc, tau3);
  kernelB<<<nblocks, 256, 0, stream>>>(pos, wlin, blin, xc, tau3, out);
}